// Round 2
// baseline (1792.675 us; speedup 1.0000x reference)
//
#include <hip/hip_runtime.h>
#include <stdint.h>

// Fused GRU-agent rollout, fp32, one block per batch element.
// T sequential steps in-kernel; weights register-resident (loaded once).
// d_out = [B*H h_final][T*B*A logits][T*B value]

#define TT  1024
#define BB  512
#define OBS 128
#define HH  64
#define AA  18

#define OFF_L (BB*HH)
#define OFF_V (OFF_L + TT*BB*AA)

__device__ __forceinline__ float fast_rcp(float x){ return __builtin_amdgcn_rcpf(x); }
__device__ __forceinline__ float sigm(float x){ return fast_rcp(1.f + __expf(-x)); }
__device__ __forceinline__ float tanh_(float x){ return 1.f - 2.f*fast_rcp(1.f + __expf(2.f*x)); }

// ---- mask-dtype detection: if any uint32 word of the mask buffer is >1,
// the buffer is byte-packed (bool/uint8); else it's int32 0/1 words. ----
__global__ void detect_mask(const uint32_t* __restrict__ m, uint32_t* __restrict__ flag)
{
    const int n_words = (TT * BB) / 4;   // scan min(bool:512KB, int32: first quarter)
    uint32_t acc = 0;
    for (int i = blockIdx.x * blockDim.x + threadIdx.x; i < n_words;
         i += gridDim.x * blockDim.x)
        acc |= (m[i] > 1u) ? 1u : 0u;
    if (acc) flag[0] = 1u;               // benign race: all writers store 1
}

__global__ __launch_bounds__(256, 2)
void gru_agent(const float* __restrict__ x,
               const void* __restrict__ mask_raw,
               const uint32_t* __restrict__ mask_flag,
               const float* __restrict__ ic,
               const float* __restrict__ W1, const float* __restrict__ b1,
               const float* __restrict__ Wi, const float* __restrict__ bi,
               const float* __restrict__ Wh, const float* __restrict__ bhn,
               const float* __restrict__ W2, const float* __restrict__ b2,
               const float* __restrict__ Wl, const float* __restrict__ bl,
               const float* __restrict__ Wv, const float* __restrict__ bv,
               float* __restrict__ out)
{
    const int b    = blockIdx.x;      // batch element
    const int tid  = threadIdx.x;     // 0..255
    const int w    = tid >> 6;        // wave 0..3
    const int lane = tid & 63;

    const bool mask_is_u8 = (mask_flag[0] != 0);
    const uint8_t* __restrict__ m8  = (const uint8_t*)mask_raw;
    const int32_t* __restrict__ m32 = (const int32_t*)mask_raw;

    // LDS (tiny; 2 blocks/CU easily). float4-typed where read vectorized.
    __shared__ float4 x_l[2][4][9];   // 4 k-chunks of 32 floats, padded to 36
    __shared__ float4 z_l[16];        // stem output (64)
    __shared__ float4 h_l[2][16];     // h double buffer
    __shared__ float4 y_l[2][16];     // y double buffer (head pipeline)
    __shared__ float4 ic_l[16];
    __shared__ float  gi_l[192];
    __shared__ float  gh_l[192];

    // ---------------- register-resident weights ----------------
    const int js = (w << 4) | (lane >> 2);
    const int kc = lane & 3;
    float w1r[32];
    #pragma unroll
    for (int i = 0; i < 32; ++i) w1r[i] = W1[(kc*32 + i)*HH + js];
    const float b1v = b1[js];

    // Waves 0-2: wA = Wi[:,n], wB = Wh[:,n]  (n = tid, 0..191)
    // Wave  3 : wA = W2[:,lane], wB = Wl[:,lane] (lane<18) / Wv (lane==18)
    float wA[64], wB[64];
    float biv = 0.f, b2v = 0.f, blv = 0.f;
    if (w < 3) {
        const int n = tid;
        #pragma unroll
        for (int k = 0; k < 64; ++k) wA[k] = Wi[k*(3*HH) + n];
        #pragma unroll
        for (int k = 0; k < 64; ++k) wB[k] = Wh[k*(3*HH) + n];
        biv = bi[n];
    } else {
        #pragma unroll
        for (int k = 0; k < 64; ++k) wA[k] = W2[k*HH + lane];
        #pragma unroll
        for (int k = 0; k < 64; ++k) wB[k] = (lane < AA) ? Wl[k*AA + lane]
                                           : (lane == AA ? Wv[k] : 0.f);
        b2v = b2[lane];
        blv = (lane < AA) ? bl[lane] : (lane == AA ? bv[0] : 0.f);
    }
    const float bhnv = (tid < HH) ? bhn[tid] : 0.f;

    // ---------------- init LDS state ----------------
    if (tid < HH) {
        float v = ic[b*HH + tid];
        ((float*)ic_l)[tid]   = v;
        ((float*)h_l[0])[tid] = v;    // h input to step 0
    }
    if (tid < OBS) {
        float xv = x[(0*BB + b)*OBS + tid];
        ((float*)&x_l[0][tid>>5])[tid&31] = xv;
    }
    uint8_t m_cur = mask_is_u8 ? m8[b] : (uint8_t)(m32[b] != 0);
    __syncthreads();

    // ---------------- T-loop (2 drain iters for head pipeline) ----------------
    for (int t = 0; t < TT + 2; ++t) {
        const int p = t & 1;

        // prefetch next x / mask into registers (hidden under compute)
        float xnext = 0.f;
        if (t + 1 < TT && tid < OBS) xnext = x[((t+1)*BB + b)*OBS + tid];
        uint8_t m_next = 0;
        if (t + 1 < TT) {
            const int mi = (t+1)*BB + b;
            m_next = mask_is_u8 ? m8[mi] : (uint8_t)(m32[mi] != 0);
        }

        // ---- phase 1a: stem partial (all waves) ----
        if (t < TT) {
            const float4* xr = &x_l[p][kc][0];
            float acc = 0.f;
            #pragma unroll
            for (int q = 0; q < 8; ++q) {
                float4 xv = xr[q];
                acc += w1r[4*q+0]*xv.x + w1r[4*q+1]*xv.y
                     + w1r[4*q+2]*xv.z + w1r[4*q+3]*xv.w;
            }
            acc += __shfl_xor(acc, 1);
            acc += __shfl_xor(acc, 2);
            if (kc == 0) ((float*)z_l)[js] = fmaxf(acc + b1v, 0.f);
        }

        // ---- phase 1b: gh (waves 0-2) | y = relu(h[t-1]@W2+b2) (wave 3) ----
        if (t < TT && w < 3) {
            const float4* hs = m_cur ? ic_l : h_l[p];   // masked episode reset
            float acc = 0.f;
            #pragma unroll
            for (int kk = 0; kk < 16; ++kk) {
                float4 hv = hs[kk];
                acc += wB[4*kk+0]*hv.x + wB[4*kk+1]*hv.y
                     + wB[4*kk+2]*hv.z + wB[4*kk+3]*hv.w;
            }
            gh_l[tid] = acc;
        } else if (w == 3 && t >= 1 && t <= TT) {
            const float4* hs = h_l[p];                  // = ys[t-1] (post-update h)
            float acc = b2v;
            #pragma unroll
            for (int kk = 0; kk < 16; ++kk) {
                float4 hv = hs[kk];
                acc += wA[4*kk+0]*hv.x + wA[4*kk+1]*hv.y
                     + wA[4*kk+2]*hv.z + wA[4*kk+3]*hv.w;
            }
            ((float*)y_l[p])[lane] = fmaxf(acc, 0.f);
        }
        __syncthreads();   // B0: z_l ready (gi needs it)

        // ---- phase 2: gi (waves 0-2) | logits/value for step t-2 (wave 3) ----
        if (t < TT && w < 3) {
            float acc = biv;
            #pragma unroll
            for (int kk = 0; kk < 16; ++kk) {
                float4 zv = z_l[kk];
                acc += wA[4*kk+0]*zv.x + wA[4*kk+1]*zv.y
                     + wA[4*kk+2]*zv.z + wA[4*kk+3]*zv.w;
            }
            gi_l[tid] = acc;
        } else if (w == 3 && t >= 2) {                  // t-2 in [0, T-1]
            const float4* ys = y_l[p ^ 1];
            float acc = blv;
            #pragma unroll
            for (int kk = 0; kk < 16; ++kk) {
                float4 yv = ys[kk];
                acc += wB[4*kk+0]*yv.x + wB[4*kk+1]*yv.y
                     + wB[4*kk+2]*yv.z + wB[4*kk+3]*yv.w;
            }
            if (lane < AA)       out[OFF_L + (size_t)((t-2)*BB + b)*AA + lane] = acc;
            else if (lane == AA) out[OFF_V + (size_t)(t-2)*BB + b] = acc;
        }
        __syncthreads();   // B1: gi_l/gh_l ready

        // ---- phase 3: elementwise GRU update (wave 0) ----
        if (t < TT && tid < HH) {
            const int j = tid;
            const float irv = gi_l[j], izv = gi_l[HH+j], inn = gi_l[2*HH+j];
            const float hrv = gh_l[j], hzv = gh_l[HH+j], hnv = gh_l[2*HH+j];
            const float heff = m_cur ? ((const float*)ic_l)[j]
                                     : ((const float*)h_l[p])[j];
            const float r  = sigm(irv + hrv);
            const float u  = sigm(izv + hzv);
            const float nn = tanh_(inn + r*(hnv + bhnv));
            ((float*)h_l[p ^ 1])[j] = u*(heff - nn) + nn;
        }
        // stage next x into LDS (loads issued at iter start)
        if (t + 1 < TT && tid < OBS) {
            ((float*)&x_l[p ^ 1][tid>>5])[tid&31] = xnext;
        }
        m_cur = m_next;
        __syncthreads();   // B2: h/x/y published for next iter
    }

    // h_final = h after step T-1, lives in h_l[TT&1]
    if (tid < HH) out[(size_t)b*HH + tid] = ((const float*)h_l[TT & 1])[tid];
}

extern "C" void kernel_launch(void* const* d_in, const int* in_sizes, int n_in,
                              void* d_out, int out_size, void* d_ws, size_t ws_size,
                              hipStream_t stream) {
    const float*   x    = (const float*)  d_in[0];
    const void*    mask = (const void*)   d_in[1];   // dtype auto-detected
    const float*   ic   = (const float*)  d_in[2];
    const float*   W1   = (const float*)  d_in[3];
    const float*   b1   = (const float*)  d_in[4];
    const float*   Wi   = (const float*)  d_in[5];
    const float*   bi   = (const float*)  d_in[6];
    const float*   Wh   = (const float*)  d_in[7];
    const float*   bhn  = (const float*)  d_in[8];
    const float*   W2   = (const float*)  d_in[9];
    const float*   b2   = (const float*)  d_in[10];
    const float*   Wl   = (const float*)  d_in[11];
    const float*   bl   = (const float*)  d_in[12];
    const float*   Wv   = (const float*)  d_in[13];
    const float*   bv   = (const float*)  d_in[14];
    float* out = (float*)d_out;

    uint32_t* flag = (uint32_t*)d_ws;
    hipMemsetAsync(flag, 0, sizeof(uint32_t), stream);
    detect_mask<<<64, 256, 0, stream>>>((const uint32_t*)mask, flag);
    gru_agent<<<BB, 256, 0, stream>>>(x, mask, flag, ic, W1, b1, Wi, bi, Wh, bhn,
                                      W2, b2, Wl, bl, Wv, bv, out);
}